// Round 3
// baseline (194.312 us; speedup 1.0000x reference)
//
#include <hip/hip_runtime.h>
#include <stdint.h>

// NextPanelHead: logits[b,i,j] = P[b,i] . W . P[b,j] + bias
// B=8, N=2048, D=384. PW = P@W (GEMM1), logits = PW @ P^T (GEMM2), fp16 MFMA
// (threshold 2.38 licenses 16-bit inputs), fp32 accumulate.
// Round 3: fuse cast+transpose (one prep kernel); GEMM1 retiled to 128x64
// (768 blocks = 3/CU vs 384 = 1.5/CU load imbalance). GEMM2 unchanged:
// 32x32x16 MFMA, BK=64, XOR bank swizzle, global_load_lds width=16 —
// within ~1.4x of its 134 MB write floor.

#define BATCH 8
#define NSEQ  2048
#define DDIM  384
#define BM 128
#define BN 128
#define BK 64

typedef __attribute__((ext_vector_type(8)))  _Float16 half8;
typedef __attribute__((ext_vector_type(4)))  _Float16 half4;
typedef __attribute__((ext_vector_type(16))) float    f32x16;

#define NP (BATCH * NSEQ * DDIM)   // 6,291,456
#define CAST_BLOCKS 1024

// ---- prep: cast P fp32->fp16 (blocks 0..1023) + transpose-cast W (rest) ----
__global__ void prep_kernel(const float* __restrict__ P,
                            const float* __restrict__ W,
                            _Float16* __restrict__ Ph,
                            _Float16* __restrict__ Wt) {
    if (blockIdx.x < CAST_BLOCKS) {
        int i = (blockIdx.x * 256 + threadIdx.x) * 4;
        const int stride = CAST_BLOCKS * 256 * 4;
        for (; i < NP; i += stride) {
            float4 f = *(const float4*)(P + i);
            half4 h;
            h.x = (_Float16)f.x; h.y = (_Float16)f.y;
            h.z = (_Float16)f.z; h.w = (_Float16)f.w;
            *(half4*)(Ph + i) = h;
        }
    } else {
        int o = (blockIdx.x - CAST_BLOCKS) * 256 + threadIdx.x;  // o = e*384+d
        if (o < DDIM * DDIM) {
            int e = o / DDIM;
            int d = o - e * DDIM;
            Wt[o] = (_Float16)W[d * DDIM + e];
        }
    }
}

// ---- GEMM1: PW[16384x384] = Ph[16384x384] . Wt^T, 128x64 tile, fp16 out ----
// 4 waves stacked in rows (32 rows each), 2 col-tiles of 32 per wave.
__global__ __launch_bounds__(256, 2) void gemm1_kernel(
    const _Float16* __restrict__ A,     // 16384 x 384
    const _Float16* __restrict__ Bmat,  // 384 x 384 (Wt = W^T)
    _Float16* __restrict__ C) {         // 16384 x 384
    __shared__ _Float16 As[BM * BK];    // 16 KB
    __shared__ _Float16 Bs[64 * BK];    // 8 KB

    const _Float16* Ab = A + (size_t)blockIdx.y * BM * DDIM;
    const _Float16* Bb = Bmat + (size_t)blockIdx.x * 64 * DDIM;

    const int tid  = threadIdx.x;
    const int wave = tid >> 6;    // 0..3 = row band
    const int lane = tid & 63;
    const int lm   = lane & 31;
    const int hi   = lane >> 5;

    const int srow = tid >> 3;                      // 0..31
    const int scg  = ((tid & 7) ^ (srow & 7)) * 8;  // swizzled global k off

    const int h0    = (hi ^ (lm & 7)) * 16;
    const int baseA = (wave * 32 + lm) * (BK * 2) + h0;
    const int baseB0 = lm * (BK * 2) + h0;
    const int baseB1 = (32 + lm) * (BK * 2) + h0;
    const char* AsB = (const char*)As;
    const char* BsB = (const char*)Bs;

    f32x16 acc0, acc1;
#pragma unroll
    for (int r = 0; r < 16; ++r) { acc0[r] = 0.f; acc1[r] = 0.f; }

    for (int k0 = 0; k0 < DDIM; k0 += BK) {
#pragma unroll
        for (int p = 0; p < 4; ++p) {
            __builtin_amdgcn_global_load_lds(
                (const __attribute__((address_space(1))) void*)
                    (Ab + (size_t)(p * 32 + srow) * DDIM + k0 + scg),
                (__attribute__((address_space(3))) void*)
                    (As + (p * 256 + tid) * 8),
                16, 0, 0);
        }
#pragma unroll
        for (int p = 0; p < 2; ++p) {
            __builtin_amdgcn_global_load_lds(
                (const __attribute__((address_space(1))) void*)
                    (Bb + (size_t)(p * 32 + srow) * DDIM + k0 + scg),
                (__attribute__((address_space(3))) void*)
                    (Bs + (p * 256 + tid) * 8),
                16, 0, 0);
        }
        __syncthreads();
#pragma unroll
        for (int s = 0; s < 4; ++s) {
            const int sx = s * 32;
            half8 a  = *(const half8*)(AsB + (baseA ^ sx));
            half8 b0 = *(const half8*)(BsB + (baseB0 ^ sx));
            half8 b1 = *(const half8*)(BsB + (baseB1 ^ sx));
            acc0 = __builtin_amdgcn_mfma_f32_32x32x16_f16(a, b0, acc0, 0, 0, 0);
            acc1 = __builtin_amdgcn_mfma_f32_32x32x16_f16(a, b1, acc1, 0, 0, 0);
        }
        __syncthreads();
    }

    const size_t row_base = (size_t)blockIdx.y * BM + wave * 32;
    const size_t col_base = (size_t)blockIdx.x * 64;
#pragma unroll
    for (int reg = 0; reg < 16; ++reg) {
        const int rin = (reg & 3) + 8 * (reg >> 2) + 4 * hi;
        _Float16* row = C + (row_base + rin) * DDIM + col_base;
        row[lm]      = (_Float16)acc0[reg];
        row[32 + lm] = (_Float16)acc1[reg];
    }
}

// ---- GEMM2: out[b] = PW[b] . Ph[b]^T + bias, 128x128 tile, fp32 out ------
__global__ __launch_bounds__(256, 2) void gemm2_kernel(
    const _Float16* __restrict__ A,     // PW: per-batch 2048 x 384
    const _Float16* __restrict__ Bmat,  // Ph: per-batch 2048 x 384
    float* __restrict__ C,              // per-batch 2048 x 2048
    const float* __restrict__ bias_ptr) {
    __shared__ _Float16 As[BM * BK];  // 16 KB
    __shared__ _Float16 Bs[BN * BK];  // 16 KB

    const size_t bstride = (size_t)NSEQ * DDIM;
    const _Float16* Ab = A + blockIdx.z * bstride
                           + (size_t)blockIdx.y * BM * DDIM;
    const _Float16* Bb = Bmat + blockIdx.z * bstride
                              + (size_t)blockIdx.x * BN * DDIM;

    const int tid  = threadIdx.x;
    const int wave = tid >> 6;
    const int lane = tid & 63;
    const int wrow = wave >> 1;   // 0..1
    const int wcol = wave & 1;    // 0..1
    const int lm   = lane & 31;
    const int hi   = lane >> 5;

    const int srow = tid >> 3;                      // 0..31
    const int scg  = ((tid & 7) ^ (srow & 7)) * 8;  // swizzled global k off

    const int h0     = (hi ^ (lm & 7)) * 16;
    const int baseA0 = (wrow * 64 + lm) * (BK * 2) + h0;
    const int baseA1 = baseA0 + 32 * (BK * 2);
    const int baseB0 = (wcol * 64 + lm) * (BK * 2) + h0;
    const int baseB1 = baseB0 + 32 * (BK * 2);
    const char* AsB = (const char*)As;
    const char* BsB = (const char*)Bs;

    f32x16 acc[2][2];
#pragma unroll
    for (int i = 0; i < 2; ++i)
#pragma unroll
        for (int j = 0; j < 2; ++j)
#pragma unroll
            for (int r = 0; r < 16; ++r)
                acc[i][j][r] = 0.f;

    for (int k0 = 0; k0 < DDIM; k0 += BK) {
#pragma unroll
        for (int p = 0; p < 4; ++p) {
            const int r = p * 32 + srow;
            __builtin_amdgcn_global_load_lds(
                (const __attribute__((address_space(1))) void*)
                    (Ab + (size_t)r * DDIM + k0 + scg),
                (__attribute__((address_space(3))) void*)
                    (As + (p * 256 + tid) * 8),
                16, 0, 0);
            __builtin_amdgcn_global_load_lds(
                (const __attribute__((address_space(1))) void*)
                    (Bb + (size_t)r * DDIM + k0 + scg),
                (__attribute__((address_space(3))) void*)
                    (Bs + (p * 256 + tid) * 8),
                16, 0, 0);
        }
        __syncthreads();
#pragma unroll
        for (int s = 0; s < 4; ++s) {
            const int sx = s * 32;
            half8 a0 = *(const half8*)(AsB + (baseA0 ^ sx));
            half8 a1 = *(const half8*)(AsB + (baseA1 ^ sx));
            half8 b0 = *(const half8*)(BsB + (baseB0 ^ sx));
            half8 b1 = *(const half8*)(BsB + (baseB1 ^ sx));
            acc[0][0] = __builtin_amdgcn_mfma_f32_32x32x16_f16(a0, b0, acc[0][0], 0, 0, 0);
            acc[0][1] = __builtin_amdgcn_mfma_f32_32x32x16_f16(a0, b1, acc[0][1], 0, 0, 0);
            acc[1][0] = __builtin_amdgcn_mfma_f32_32x32x16_f16(a1, b0, acc[1][0], 0, 0, 0);
            acc[1][1] = __builtin_amdgcn_mfma_f32_32x32x16_f16(a1, b1, acc[1][1], 0, 0, 0);
        }
        __syncthreads();
    }

    // C/D layout: col = lane&31, row = (reg&3) + 8*(reg>>2) + 4*hi.
    const float bias = bias_ptr[0];
    float* Cb = C + (size_t)blockIdx.z * NSEQ * NSEQ;
    const size_t row_base = (size_t)blockIdx.y * BM + wrow * 64;
    const size_t col_base = (size_t)blockIdx.x * BN + wcol * 64;
#pragma unroll
    for (int i = 0; i < 2; ++i)
#pragma unroll
        for (int j = 0; j < 2; ++j)
#pragma unroll
            for (int reg = 0; reg < 16; ++reg) {
                const int rin = (reg & 3) + 8 * (reg >> 2) + 4 * hi;
                Cb[(row_base + i * 32 + rin) * NSEQ
                   + col_base + j * 32 + lm] = acc[i][j][reg] + bias;
            }
}

extern "C" void kernel_launch(void* const* d_in, const int* in_sizes, int n_in,
                              void* d_out, int out_size, void* d_ws,
                              size_t ws_size, hipStream_t stream) {
    const float* P  = (const float*)d_in[0];  // [8,2048,384]
    const float* W  = (const float*)d_in[1];  // [384,384]
    const float* bp = (const float*)d_in[2];  // [1]
    float* out = (float*)d_out;               // [8,2048,2048]

    // workspace (fp16): Ph 12.6MB | Wt 0.3MB | PW 12.6MB
    _Float16* Ph = (_Float16*)d_ws;
    _Float16* Wt = Ph + (size_t)NP;
    _Float16* PW = Wt + (size_t)DDIM * DDIM;

    const int wblocks = (DDIM * DDIM + 255) / 256;  // 576
    prep_kernel<<<CAST_BLOCKS + wblocks, 256, 0, stream>>>(P, W, Ph, Wt);

    // GEMM1: 128x64 tiles -> grid (6, 128) = 768 blocks (3 per CU)
    dim3 g1(DDIM / 64, (BATCH * NSEQ) / BM, 1);
    gemm1_kernel<<<g1, 256, 0, stream>>>(Ph, Wt, PW);

    // GEMM2: 128x128 tiles -> grid (16, 16, 8) = 2048 blocks
    dim3 g2(NSEQ / BN, NSEQ / BM, BATCH);
    gemm2_kernel<<<g2, 256, 0, stream>>>(PW, Ph, out, bp);
}

// Round 4
// 183.163 us; speedup vs baseline: 1.0609x; 1.0609x over previous
//
#include <hip/hip_runtime.h>
#include <stdint.h>

// NextPanelHead: logits[b,i,j] = P[b,i] . W . P[b,j] + bias
// B=8, N=2048, D=384. PW = P@W (GEMM1), logits = PW @ P^T (GEMM2), fp16 MFMA
// (threshold 2.38 licenses 16-bit inputs), fp32 accumulate.
// Round 4: XCD-aware block swizzle (n%8 -> XCD round-robin assumption).
// GEMM2: XCD = batch -> each XCD's 4MiB L2 holds its batch's PW+Ph (3.1 MB),
// turning ~400 MB of cross-XCD L3 fetch into L2 hits. GEMM1: each XCD owns
// 16 row-tiles (1.5 MB A + 288 KB Wt resident). Kernel bodies unchanged from
// R3 (32x32x16 MFMA, BK=64, XOR LDS swizzle, global_load_lds w=16).

#define BATCH 8
#define NSEQ  2048
#define DDIM  384
#define BM 128
#define BN 128
#define BK 64

typedef __attribute__((ext_vector_type(8)))  _Float16 half8;
typedef __attribute__((ext_vector_type(4)))  _Float16 half4;
typedef __attribute__((ext_vector_type(16))) float    f32x16;

#define NP (BATCH * NSEQ * DDIM)   // 6,291,456
#define CAST_BLOCKS 1024

// ---- prep: cast P fp32->fp16 (blocks 0..1023) + transpose-cast W (rest) ----
__global__ void prep_kernel(const float* __restrict__ P,
                            const float* __restrict__ W,
                            _Float16* __restrict__ Ph,
                            _Float16* __restrict__ Wt) {
    if (blockIdx.x < CAST_BLOCKS) {
        int i = (blockIdx.x * 256 + threadIdx.x) * 4;
        const int stride = CAST_BLOCKS * 256 * 4;
        for (; i < NP; i += stride) {
            float4 f = *(const float4*)(P + i);
            half4 h;
            h.x = (_Float16)f.x; h.y = (_Float16)f.y;
            h.z = (_Float16)f.z; h.w = (_Float16)f.w;
            *(half4*)(Ph + i) = h;
        }
    } else {
        int o = (blockIdx.x - CAST_BLOCKS) * 256 + threadIdx.x;  // o = e*384+d
        if (o < DDIM * DDIM) {
            int e = o / DDIM;
            int d = o - e * DDIM;
            Wt[o] = (_Float16)W[d * DDIM + e];
        }
    }
}

// ---- GEMM1: PW[16384x384] = Ph[16384x384] . Wt^T, 128x64 tile, fp16 out ----
// 1D grid of 768; XCD swizzle: xcd = n&7 owns y in {xcd, xcd+8, ...} (16 rows)
__global__ __launch_bounds__(256, 2) void gemm1_kernel(
    const _Float16* __restrict__ A,     // 16384 x 384
    const _Float16* __restrict__ Bmat,  // 384 x 384 (Wt = W^T)
    _Float16* __restrict__ C) {         // 16384 x 384
    __shared__ _Float16 As[BM * BK];    // 16 KB
    __shared__ _Float16 Bs[64 * BK];    // 8 KB

    const int n   = blockIdx.x;
    const int xcd = n & 7;
    const int i2  = n >> 3;        // 0..95
    const int bx  = i2 % 6;        // col tile 0..5
    const int by  = xcd + 8 * (i2 / 6);  // row tile 0..127

    const _Float16* Ab = A + (size_t)by * BM * DDIM;
    const _Float16* Bb = Bmat + (size_t)bx * 64 * DDIM;

    const int tid  = threadIdx.x;
    const int wave = tid >> 6;    // 0..3 = row band
    const int lane = tid & 63;
    const int lm   = lane & 31;
    const int hi   = lane >> 5;

    const int srow = tid >> 3;                      // 0..31
    const int scg  = ((tid & 7) ^ (srow & 7)) * 8;  // swizzled global k off

    const int h0    = (hi ^ (lm & 7)) * 16;
    const int baseA = (wave * 32 + lm) * (BK * 2) + h0;
    const int baseB0 = lm * (BK * 2) + h0;
    const int baseB1 = (32 + lm) * (BK * 2) + h0;
    const char* AsB = (const char*)As;
    const char* BsB = (const char*)Bs;

    f32x16 acc0, acc1;
#pragma unroll
    for (int r = 0; r < 16; ++r) { acc0[r] = 0.f; acc1[r] = 0.f; }

    for (int k0 = 0; k0 < DDIM; k0 += BK) {
#pragma unroll
        for (int p = 0; p < 4; ++p) {
            __builtin_amdgcn_global_load_lds(
                (const __attribute__((address_space(1))) void*)
                    (Ab + (size_t)(p * 32 + srow) * DDIM + k0 + scg),
                (__attribute__((address_space(3))) void*)
                    (As + (p * 256 + tid) * 8),
                16, 0, 0);
        }
#pragma unroll
        for (int p = 0; p < 2; ++p) {
            __builtin_amdgcn_global_load_lds(
                (const __attribute__((address_space(1))) void*)
                    (Bb + (size_t)(p * 32 + srow) * DDIM + k0 + scg),
                (__attribute__((address_space(3))) void*)
                    (Bs + (p * 256 + tid) * 8),
                16, 0, 0);
        }
        __syncthreads();
#pragma unroll
        for (int s = 0; s < 4; ++s) {
            const int sx = s * 32;
            half8 a  = *(const half8*)(AsB + (baseA ^ sx));
            half8 b0 = *(const half8*)(BsB + (baseB0 ^ sx));
            half8 b1 = *(const half8*)(BsB + (baseB1 ^ sx));
            acc0 = __builtin_amdgcn_mfma_f32_32x32x16_f16(a, b0, acc0, 0, 0, 0);
            acc1 = __builtin_amdgcn_mfma_f32_32x32x16_f16(a, b1, acc1, 0, 0, 0);
        }
        __syncthreads();
    }

    const size_t row_base = (size_t)by * BM + wave * 32;
    const size_t col_base = (size_t)bx * 64;
#pragma unroll
    for (int reg = 0; reg < 16; ++reg) {
        const int rin = (reg & 3) + 8 * (reg >> 2) + 4 * hi;
        _Float16* row = C + (row_base + rin) * DDIM + col_base;
        row[lm]      = (_Float16)acc0[reg];
        row[32 + lm] = (_Float16)acc1[reg];
    }
}

// ---- GEMM2: out[b] = PW[b] . Ph[b]^T + bias, 128x128 tile, fp32 out ------
// 1D grid of 2048; XCD swizzle: xcd = n&7 = batch z -> each XCD's L2 holds
// its batch's PW (1.57 MB) + Ph (1.57 MB); all tile reuse served from L2.
__global__ __launch_bounds__(256, 2) void gemm2_kernel(
    const _Float16* __restrict__ A,     // PW: per-batch 2048 x 384
    const _Float16* __restrict__ Bmat,  // Ph: per-batch 2048 x 384
    float* __restrict__ C,              // per-batch 2048 x 2048
    const float* __restrict__ bias_ptr) {
    __shared__ _Float16 As[BM * BK];  // 16 KB
    __shared__ _Float16 Bs[BN * BK];  // 16 KB

    const int n  = blockIdx.x;
    const int z  = n & 7;          // batch == XCD (round-robin assumption)
    const int i2 = n >> 3;         // 0..255
    const int bx = i2 & 15;
    const int by = i2 >> 4;

    const size_t bstride = (size_t)NSEQ * DDIM;
    const _Float16* Ab = A + (size_t)z * bstride + (size_t)by * BM * DDIM;
    const _Float16* Bb = Bmat + (size_t)z * bstride + (size_t)bx * BN * DDIM;

    const int tid  = threadIdx.x;
    const int wave = tid >> 6;
    const int lane = tid & 63;
    const int wrow = wave >> 1;   // 0..1
    const int wcol = wave & 1;    // 0..1
    const int lm   = lane & 31;
    const int hi   = lane >> 5;

    const int srow = tid >> 3;                      // 0..31
    const int scg  = ((tid & 7) ^ (srow & 7)) * 8;  // swizzled global k off

    const int h0     = (hi ^ (lm & 7)) * 16;
    const int baseA0 = (wrow * 64 + lm) * (BK * 2) + h0;
    const int baseA1 = baseA0 + 32 * (BK * 2);
    const int baseB0 = (wcol * 64 + lm) * (BK * 2) + h0;
    const int baseB1 = baseB0 + 32 * (BK * 2);
    const char* AsB = (const char*)As;
    const char* BsB = (const char*)Bs;

    f32x16 acc[2][2];
#pragma unroll
    for (int i = 0; i < 2; ++i)
#pragma unroll
        for (int j = 0; j < 2; ++j)
#pragma unroll
            for (int r = 0; r < 16; ++r)
                acc[i][j][r] = 0.f;

    for (int k0 = 0; k0 < DDIM; k0 += BK) {
#pragma unroll
        for (int p = 0; p < 4; ++p) {
            const int r = p * 32 + srow;
            __builtin_amdgcn_global_load_lds(
                (const __attribute__((address_space(1))) void*)
                    (Ab + (size_t)r * DDIM + k0 + scg),
                (__attribute__((address_space(3))) void*)
                    (As + (p * 256 + tid) * 8),
                16, 0, 0);
            __builtin_amdgcn_global_load_lds(
                (const __attribute__((address_space(1))) void*)
                    (Bb + (size_t)r * DDIM + k0 + scg),
                (__attribute__((address_space(3))) void*)
                    (Bs + (p * 256 + tid) * 8),
                16, 0, 0);
        }
        __syncthreads();
#pragma unroll
        for (int s = 0; s < 4; ++s) {
            const int sx = s * 32;
            half8 a0 = *(const half8*)(AsB + (baseA0 ^ sx));
            half8 a1 = *(const half8*)(AsB + (baseA1 ^ sx));
            half8 b0 = *(const half8*)(BsB + (baseB0 ^ sx));
            half8 b1 = *(const half8*)(BsB + (baseB1 ^ sx));
            acc[0][0] = __builtin_amdgcn_mfma_f32_32x32x16_f16(a0, b0, acc[0][0], 0, 0, 0);
            acc[0][1] = __builtin_amdgcn_mfma_f32_32x32x16_f16(a0, b1, acc[0][1], 0, 0, 0);
            acc[1][0] = __builtin_amdgcn_mfma_f32_32x32x16_f16(a1, b0, acc[1][0], 0, 0, 0);
            acc[1][1] = __builtin_amdgcn_mfma_f32_32x32x16_f16(a1, b1, acc[1][1], 0, 0, 0);
        }
        __syncthreads();
    }

    // C/D layout: col = lane&31, row = (reg&3) + 8*(reg>>2) + 4*hi.
    const float bias = bias_ptr[0];
    float* Cb = C + (size_t)z * NSEQ * NSEQ;
    const size_t row_base = (size_t)by * BM + wrow * 64;
    const size_t col_base = (size_t)bx * BN + wcol * 64;
#pragma unroll
    for (int i = 0; i < 2; ++i)
#pragma unroll
        for (int j = 0; j < 2; ++j)
#pragma unroll
            for (int reg = 0; reg < 16; ++reg) {
                const int rin = (reg & 3) + 8 * (reg >> 2) + 4 * hi;
                Cb[(row_base + i * 32 + rin) * NSEQ
                   + col_base + j * 32 + lm] = acc[i][j][reg] + bias;
            }
}

extern "C" void kernel_launch(void* const* d_in, const int* in_sizes, int n_in,
                              void* d_out, int out_size, void* d_ws,
                              size_t ws_size, hipStream_t stream) {
    const float* P  = (const float*)d_in[0];  // [8,2048,384]
    const float* W  = (const float*)d_in[1];  // [384,384]
    const float* bp = (const float*)d_in[2];  // [1]
    float* out = (float*)d_out;               // [8,2048,2048]

    // workspace (fp16): Ph 12.6MB | Wt 0.3MB | PW 12.6MB
    _Float16* Ph = (_Float16*)d_ws;
    _Float16* Wt = Ph + (size_t)NP;
    _Float16* PW = Wt + (size_t)DDIM * DDIM;

    const int wblocks = (DDIM * DDIM + 255) / 256;  // 576
    prep_kernel<<<CAST_BLOCKS + wblocks, 256, 0, stream>>>(P, W, Ph, Wt);

    // GEMM1: 768 blocks (1D, XCD-swizzled decode inside)
    gemm1_kernel<<<768, 256, 0, stream>>>(Ph, Wt, PW);

    // GEMM2: 2048 blocks (1D, xcd = batch decode inside)
    gemm2_kernel<<<2048, 256, 0, stream>>>(PW, Ph, out, bp);
}

// Round 5
// 178.952 us; speedup vs baseline: 1.0858x; 1.0235x over previous
//
#include <hip/hip_runtime.h>
#include <stdint.h>

// NextPanelHead: logits[b,i,j] = P[b,i] . W . P[b,j] + bias
// B=8, N=2048, D=384. PW = P@W (GEMM1), logits = PW @ P^T (GEMM2), fp16 MFMA
// (threshold 2.38 licenses 16-bit inputs), fp32 accumulate.
// Round 5: __launch_bounds__(256,4) -> 4 blocks/CU (was 2). Only 6 K-stages
// per block: the vmcnt(0)+barrier drain and the 64-store epilogue burst need
// more resident waves to overlap (m114: waves co-schedule across pipes).
// VGPR budget: acc 64 + frags 16 + addr ~25 < 128, no spill expected.
// Unchanged: 32x32x16 MFMA, BK=64, XOR LDS swizzle, global_load_lds w=16,
// XCD-aware decode (n&7 -> XCD; GEMM2 pins batch to XCD, 3.1 MB L2-resident).

#define BATCH 8
#define NSEQ  2048
#define DDIM  384
#define BM 128
#define BN 128
#define BK 64

typedef __attribute__((ext_vector_type(8)))  _Float16 half8;
typedef __attribute__((ext_vector_type(4)))  _Float16 half4;
typedef __attribute__((ext_vector_type(16))) float    f32x16;

#define NP (BATCH * NSEQ * DDIM)   // 6,291,456
#define CAST_BLOCKS 1024

// ---- prep: cast P fp32->fp16 (blocks 0..1023) + transpose-cast W (rest) ----
__global__ void prep_kernel(const float* __restrict__ P,
                            const float* __restrict__ W,
                            _Float16* __restrict__ Ph,
                            _Float16* __restrict__ Wt) {
    if (blockIdx.x < CAST_BLOCKS) {
        int i = (blockIdx.x * 256 + threadIdx.x) * 8;
        const int stride = CAST_BLOCKS * 256 * 8;
        for (; i < NP; i += stride) {
            float4 f0 = *(const float4*)(P + i);
            float4 f1 = *(const float4*)(P + i + 4);
            half8 h;
            h[0] = (_Float16)f0.x; h[1] = (_Float16)f0.y;
            h[2] = (_Float16)f0.z; h[3] = (_Float16)f0.w;
            h[4] = (_Float16)f1.x; h[5] = (_Float16)f1.y;
            h[6] = (_Float16)f1.z; h[7] = (_Float16)f1.w;
            *(half8*)(Ph + i) = h;
        }
    } else {
        int o = (blockIdx.x - CAST_BLOCKS) * 256 + threadIdx.x;  // o = e*384+d
        if (o < DDIM * DDIM) {
            int e = o / DDIM;
            int d = o - e * DDIM;
            Wt[o] = (_Float16)W[d * DDIM + e];
        }
    }
}

// ---- GEMM1: PW[16384x384] = Ph[16384x384] . Wt^T, 128x64 tile, fp16 out ----
// 1D grid of 768; XCD swizzle: xcd = n&7 owns y in {xcd, xcd+8, ...} (16 rows)
__global__ __launch_bounds__(256, 4) void gemm1_kernel(
    const _Float16* __restrict__ A,     // 16384 x 384
    const _Float16* __restrict__ Bmat,  // 384 x 384 (Wt = W^T)
    _Float16* __restrict__ C) {         // 16384 x 384
    __shared__ _Float16 As[BM * BK];    // 16 KB
    __shared__ _Float16 Bs[64 * BK];    // 8 KB

    const int n   = blockIdx.x;
    const int xcd = n & 7;
    const int i2  = n >> 3;        // 0..95
    const int bx  = i2 % 6;        // col tile 0..5
    const int by  = xcd + 8 * (i2 / 6);  // row tile 0..127

    const _Float16* Ab = A + (size_t)by * BM * DDIM;
    const _Float16* Bb = Bmat + (size_t)bx * 64 * DDIM;

    const int tid  = threadIdx.x;
    const int wave = tid >> 6;    // 0..3 = row band
    const int lane = tid & 63;
    const int lm   = lane & 31;
    const int hi   = lane >> 5;

    const int srow = tid >> 3;                      // 0..31
    const int scg  = ((tid & 7) ^ (srow & 7)) * 8;  // swizzled global k off

    const int h0    = (hi ^ (lm & 7)) * 16;
    const int baseA = (wave * 32 + lm) * (BK * 2) + h0;
    const int baseB0 = lm * (BK * 2) + h0;
    const int baseB1 = (32 + lm) * (BK * 2) + h0;
    const char* AsB = (const char*)As;
    const char* BsB = (const char*)Bs;

    f32x16 acc0, acc1;
#pragma unroll
    for (int r = 0; r < 16; ++r) { acc0[r] = 0.f; acc1[r] = 0.f; }

    for (int k0 = 0; k0 < DDIM; k0 += BK) {
#pragma unroll
        for (int p = 0; p < 4; ++p) {
            __builtin_amdgcn_global_load_lds(
                (const __attribute__((address_space(1))) void*)
                    (Ab + (size_t)(p * 32 + srow) * DDIM + k0 + scg),
                (__attribute__((address_space(3))) void*)
                    (As + (p * 256 + tid) * 8),
                16, 0, 0);
        }
#pragma unroll
        for (int p = 0; p < 2; ++p) {
            __builtin_amdgcn_global_load_lds(
                (const __attribute__((address_space(1))) void*)
                    (Bb + (size_t)(p * 32 + srow) * DDIM + k0 + scg),
                (__attribute__((address_space(3))) void*)
                    (Bs + (p * 256 + tid) * 8),
                16, 0, 0);
        }
        __syncthreads();
#pragma unroll
        for (int s = 0; s < 4; ++s) {
            const int sx = s * 32;
            half8 a  = *(const half8*)(AsB + (baseA ^ sx));
            half8 b0 = *(const half8*)(BsB + (baseB0 ^ sx));
            half8 b1 = *(const half8*)(BsB + (baseB1 ^ sx));
            acc0 = __builtin_amdgcn_mfma_f32_32x32x16_f16(a, b0, acc0, 0, 0, 0);
            acc1 = __builtin_amdgcn_mfma_f32_32x32x16_f16(a, b1, acc1, 0, 0, 0);
        }
        __syncthreads();
    }

    const size_t row_base = (size_t)by * BM + wave * 32;
    const size_t col_base = (size_t)bx * 64;
#pragma unroll
    for (int reg = 0; reg < 16; ++reg) {
        const int rin = (reg & 3) + 8 * (reg >> 2) + 4 * hi;
        _Float16* row = C + (row_base + rin) * DDIM + col_base;
        row[lm]      = (_Float16)acc0[reg];
        row[32 + lm] = (_Float16)acc1[reg];
    }
}

// ---- GEMM2: out[b] = PW[b] . Ph[b]^T + bias, 128x128 tile, fp32 out ------
// 1D grid of 2048; xcd = n&7 = batch z -> each XCD's L2 holds its batch's
// PW (1.57 MB) + Ph (1.57 MB); all tile reuse served from L2.
__global__ __launch_bounds__(256, 4) void gemm2_kernel(
    const _Float16* __restrict__ A,     // PW: per-batch 2048 x 384
    const _Float16* __restrict__ Bmat,  // Ph: per-batch 2048 x 384
    float* __restrict__ C,              // per-batch 2048 x 2048
    const float* __restrict__ bias_ptr) {
    __shared__ _Float16 As[BM * BK];  // 16 KB
    __shared__ _Float16 Bs[BN * BK];  // 16 KB

    const int n  = blockIdx.x;
    const int z  = n & 7;          // batch == XCD (round-robin, verified R4)
    const int i2 = n >> 3;         // 0..255
    const int bx = i2 & 15;
    const int by = i2 >> 4;

    const size_t bstride = (size_t)NSEQ * DDIM;
    const _Float16* Ab = A + (size_t)z * bstride + (size_t)by * BM * DDIM;
    const _Float16* Bb = Bmat + (size_t)z * bstride + (size_t)bx * BN * DDIM;

    const int tid  = threadIdx.x;
    const int wave = tid >> 6;
    const int lane = tid & 63;
    const int wrow = wave >> 1;   // 0..1
    const int wcol = wave & 1;    // 0..1
    const int lm   = lane & 31;
    const int hi   = lane >> 5;

    const int srow = tid >> 3;                      // 0..31
    const int scg  = ((tid & 7) ^ (srow & 7)) * 8;  // swizzled global k off

    const int h0     = (hi ^ (lm & 7)) * 16;
    const int baseA0 = (wrow * 64 + lm) * (BK * 2) + h0;
    const int baseA1 = baseA0 + 32 * (BK * 2);
    const int baseB0 = (wcol * 64 + lm) * (BK * 2) + h0;
    const int baseB1 = baseB0 + 32 * (BK * 2);
    const char* AsB = (const char*)As;
    const char* BsB = (const char*)Bs;

    f32x16 acc[2][2];
#pragma unroll
    for (int i = 0; i < 2; ++i)
#pragma unroll
        for (int j = 0; j < 2; ++j)
#pragma unroll
            for (int r = 0; r < 16; ++r)
                acc[i][j][r] = 0.f;

    for (int k0 = 0; k0 < DDIM; k0 += BK) {
#pragma unroll
        for (int p = 0; p < 4; ++p) {
            const int r = p * 32 + srow;
            __builtin_amdgcn_global_load_lds(
                (const __attribute__((address_space(1))) void*)
                    (Ab + (size_t)r * DDIM + k0 + scg),
                (__attribute__((address_space(3))) void*)
                    (As + (p * 256 + tid) * 8),
                16, 0, 0);
            __builtin_amdgcn_global_load_lds(
                (const __attribute__((address_space(1))) void*)
                    (Bb + (size_t)r * DDIM + k0 + scg),
                (__attribute__((address_space(3))) void*)
                    (Bs + (p * 256 + tid) * 8),
                16, 0, 0);
        }
        __syncthreads();
#pragma unroll
        for (int s = 0; s < 4; ++s) {
            const int sx = s * 32;
            half8 a0 = *(const half8*)(AsB + (baseA0 ^ sx));
            half8 a1 = *(const half8*)(AsB + (baseA1 ^ sx));
            half8 b0 = *(const half8*)(BsB + (baseB0 ^ sx));
            half8 b1 = *(const half8*)(BsB + (baseB1 ^ sx));
            acc[0][0] = __builtin_amdgcn_mfma_f32_32x32x16_f16(a0, b0, acc[0][0], 0, 0, 0);
            acc[0][1] = __builtin_amdgcn_mfma_f32_32x32x16_f16(a0, b1, acc[0][1], 0, 0, 0);
            acc[1][0] = __builtin_amdgcn_mfma_f32_32x32x16_f16(a1, b0, acc[1][0], 0, 0, 0);
            acc[1][1] = __builtin_amdgcn_mfma_f32_32x32x16_f16(a1, b1, acc[1][1], 0, 0, 0);
        }
        __syncthreads();
    }

    // C/D layout: col = lane&31, row = (reg&3) + 8*(reg>>2) + 4*hi.
    const float bias = bias_ptr[0];
    float* Cb = C + (size_t)z * NSEQ * NSEQ;
    const size_t row_base = (size_t)by * BM + wrow * 64;
    const size_t col_base = (size_t)bx * BN + wcol * 64;
#pragma unroll
    for (int i = 0; i < 2; ++i)
#pragma unroll
        for (int j = 0; j < 2; ++j)
#pragma unroll
            for (int reg = 0; reg < 16; ++reg) {
                const int rin = (reg & 3) + 8 * (reg >> 2) + 4 * hi;
                Cb[(row_base + i * 32 + rin) * NSEQ
                   + col_base + j * 32 + lm] = acc[i][j][reg] + bias;
            }
}

extern "C" void kernel_launch(void* const* d_in, const int* in_sizes, int n_in,
                              void* d_out, int out_size, void* d_ws,
                              size_t ws_size, hipStream_t stream) {
    const float* P  = (const float*)d_in[0];  // [8,2048,384]
    const float* W  = (const float*)d_in[1];  // [384,384]
    const float* bp = (const float*)d_in[2];  // [1]
    float* out = (float*)d_out;               // [8,2048,2048]

    // workspace (fp16): Ph 12.6MB | Wt 0.3MB | PW 12.6MB
    _Float16* Ph = (_Float16*)d_ws;
    _Float16* Wt = Ph + (size_t)NP;
    _Float16* PW = Wt + (size_t)DDIM * DDIM;

    const int wblocks = (DDIM * DDIM + 255) / 256;  // 576
    prep_kernel<<<CAST_BLOCKS + wblocks, 256, 0, stream>>>(P, W, Ph, Wt);

    // GEMM1: 768 blocks (1D, XCD-swizzled decode inside)
    gemm1_kernel<<<768, 256, 0, stream>>>(Ph, Wt, PW);

    // GEMM2: 2048 blocks (1D, xcd = batch decode inside)
    gemm2_kernel<<<2048, 256, 0, stream>>>(PW, Ph, out, bp);
}